// Round 14
// baseline (730.362 us; speedup 1.0000x reference)
//
#include <hip/hip_runtime.h>
#include <hip/hip_bf16.h>

static constexpr int EDIM   = 128;   // embedding size
static constexpr int FIN    = 256;   // input features
static constexpr int RCAP   = 3456;  // per-256-row-range binned capacity (~3072+7sigma)
static constexpr int NBIN   = 512;   // bin blocks in k_mega
static constexpr int CSRCAP = 2048;  // per-128-row LDS CSR capacity (~1536+13sigma)

typedef __attribute__((ext_vector_type(8))) short bf16x8;
typedef __attribute__((ext_vector_type(4))) float f32x4;

__device__ inline short f2b(float f) {
    __hip_bfloat16 h = __float2bfloat16(f);
    return *reinterpret_cast<short*>(&h);
}

// ---------------------------------------------------------------------------
// Prep: fragment-major bf16 weights + scalar coefficients + zero gtail[].
//   WtF[((kt*8+nf)*64+lane)] = B-frag of W    (4096 frags, 64 KB)
//   vwF[((ks*8+nf)*64+lane)] = B-frag of vw^T (2048 frags, 32 KB)
// ---------------------------------------------------------------------------
__global__ __launch_bounds__(256) void k_prep(const float* __restrict__ W,
                                              const float* __restrict__ vw,
                                              const float* __restrict__ lg,
                                              const float* __restrict__ mg,
                                              short* __restrict__ WtF,
                                              short* __restrict__ vwF,
                                              float* __restrict__ sc,
                                              int* __restrict__ gtail) {
    const int bid = blockIdx.x, tid = threadIdx.x;
    if (bid < 16) {                                // WtF: 4096 fragments
        int idx = bid * 256 + tid;                 // (kt,nf,lane)
        int kt = idx >> 9, rem = idx & 511;
        int nf = rem >> 6, lane = rem & 63;
        int l15 = lane & 15, lhi = lane >> 4;
        bf16x8 fr;
        #pragma unroll
        for (int i = 0; i < 8; ++i)
            fr[i] = f2b(W[(size_t)(kt*32 + lhi*8 + i) * EDIM + nf*16 + l15]);
        *(bf16x8*)(WtF + (size_t)idx * 8) = fr;
    } else if (bid < 24) {                         // vwF: 2048 fragments
        int idx = (bid - 16) * 256 + tid;          // (ks,nf,lane)
        int ks = idx >> 9, rem = idx & 511;
        int nf = rem >> 6, lane = rem & 63;
        int l15 = lane & 15, lhi = lane >> 4;
        bf16x8 fr;
        #pragma unroll
        for (int i = 0; i < 8; ++i)
            fr[i] = f2b(vw[(size_t)(nf*16 + l15) * EDIM + ks*32 + lhi*8 + i]);
        *(bf16x8*)(vwF + (size_t)idx * 8) = fr;
    } else if (bid == 24) {
        if (tid == 0) {
            const float a0 = -1e-9f, a1 = 1.0f + 1e-9f;
            float a_low = 0.f, b_low = 0.f, a_mid = 0.f, c_mid = 0.f;
            for (int i = 0; i < 5; ++i) {
                float l0 = fmaxf(lg[2*i], 0.f), l1 = fmaxf(lg[2*i+1], 0.f);
                a_low += l0 * a0 + l1 * a1;
                b_low += l0 * (1.f - a0) + l1 * (1.f - a1);
                float m0 = fmaxf(mg[2*i], 0.f), m1 = fmaxf(mg[2*i+1], 0.f);
                a_mid += m0 + m1;
                c_mid += m0 * a0 + m1 * a1;
            }
            sc[0] = a_low + a_mid;
            sc[1] = b_low - c_mid;
        }
    } else {                                       // bid == 25: zero gtail
        gtail[tid] = 0;
    }
}

// ---------------------------------------------------------------------------
// Mega dispatch. 33792 B LDS union -> 4 blocks/CU:
//  blocks [0, NBIN): edge BINNING into 256-row ranges. LDS staging buffers
//    (256 ranges x 16 x 8B) flushed with LANE-PARALLEL CONTIGUOUS stores to
//    binned[rg*RCAP + tail] (atomic tail). No scattered partial-line stores
//    -> no 64B-per-store HBM writeback amplification (the r6-r13 fill tax).
//    Overflow (slot>=16, P~1e-4) falls back to a direct store.
//  blocks [NBIN, +gGemm): fused MFMA GEMM Y = relu(F@W) @ vw^T. BM=64,
//    4 waves, wave owns 16 rows; 8KB weight chunks double-buffered in LDS;
//    F loaded 2x float4 per k-step with 1-step prefetch (no spill).
// ---------------------------------------------------------------------------
__global__ __launch_bounds__(256) void k_mega(const float* __restrict__ F,
                                              const short* __restrict__ WtF,
                                              const short* __restrict__ vwF,
                                              short* __restrict__ Yb,
                                              const int* __restrict__ ei,
                                              const float* __restrict__ ew,
                                              int* __restrict__ gtail,
                                              uint2* __restrict__ binned,
                                              int M, int ne) {
    __shared__ __align__(16) unsigned char Lraw[33792];
    const int bid = blockIdx.x, tid = threadIdx.x;
    const int wave = tid >> 6, lane = tid & 63;

    if (bid < NBIN) {                // ---- bin path ----
        uint2* buf  = (uint2*)Lraw;                 // 256 ranges x 16 entries
        int*   bcnt = (int*)(Lraw + 32768);         // 256 counters
        const int perBlk = (ne + NBIN - 1) / NBIN;
        const int base = bid * perBlk;
        const int lim  = min(base + perBlk, ne);
        if (tid < 256) bcnt[tid] = 0;
        __syncthreads();
        for (int r0 = base; r0 < lim; r0 += 1024) {
            #pragma unroll
            for (int u = 0; u < 4; ++u) {
                int e = r0 + u * 256 + tid;
                if (e < lim) {
                    int row = ei[e];
                    unsigned meta = ((unsigned)(row & 255) << 16) | (unsigned)ei[ne + e];
                    unsigned wb   = __float_as_uint(ew[e]);
                    int rg = row >> 8;
                    int slot = atomicAdd(&bcnt[rg], 1);
                    if (slot < 16) buf[rg * 16 + slot] = make_uint2(meta, wb);
                    else {
                        int g = atomicAdd(&gtail[rg], 1);
                        if (g < RCAP) binned[(size_t)rg * RCAP + g] = make_uint2(meta, wb);
                    }
                }
            }
            __syncthreads();
            for (int rg = wave; rg < 256; rg += 4) {   // lane-parallel flush
                int c = bcnt[rg]; if (c > 16) c = 16;
                if (c == 0) continue;
                int gb = 0;
                if (lane == 0) gb = atomicAdd(&gtail[rg], c);
                gb = __shfl(gb, 0);
                if (lane < c && gb + lane < RCAP)
                    binned[(size_t)rg * RCAP + gb + lane] = buf[rg * 16 + lane];
            }
            __syncthreads();
            if (tid < 256) bcnt[tid] = 0;
            __syncthreads();
        }
        return;
    }

    // ---- fused GEMM path ----
    short* Sb  = (short*)Lraw;                      // 64 x 136 transpose slabs
    short* WbA = (short*)(Lraw + 17408);            // 2 x 8KB chunk dbuf
    short* WbB = (short*)(Lraw + 17408 + 8192);
    const int l15 = lane & 15, lhi = lane >> 4;
    const int bm  = (bid - NBIN) * 64;
    const int wrow = wave * 16;

    const int gr_a = bm + wrow + l15;
    const bool va  = gr_a < M;
    const float* fp = F + (size_t)(va ? gr_a : 0) * FIN + lhi * 8;

    {   // stage chunk 0 of WtF
        const int4* s = (const int4*)WtF;
        int4* d = (int4*)WbA;
        d[tid] = s[tid]; d[tid + 256] = s[tid + 256];
    }
    float4 c0 = make_float4(0.f,0.f,0.f,0.f), c1 = c0;
    if (va) { c0 = *(const float4*)(fp); c1 = *(const float4*)(fp + 4); }
    __syncthreads();

    f32x4 acc[8];
    #pragma unroll
    for (int b = 0; b < 8; ++b) acc[b] = (f32x4){0.f, 0.f, 0.f, 0.f};

    #pragma unroll
    for (int kt = 0; kt < 8; ++kt) {
        short* cur = (kt & 1) ? WbB : WbA;
        short* nxt = (kt & 1) ? WbA : WbB;
        if (kt < 7) {
            const int4* s = (const int4*)(WtF + (kt + 1) * 4096);
            int4* d = (int4*)nxt;
            d[tid] = s[tid]; d[tid + 256] = s[tid + 256];
        }
        float4 n0 = make_float4(0.f,0.f,0.f,0.f), n1 = n0;
        if (kt < 7 && va) {
            n0 = *(const float4*)(fp + (kt+1)*32);
            n1 = *(const float4*)(fp + (kt+1)*32 + 4);
        }
        bf16x8 af;
        af[0]=f2b(c0.x); af[1]=f2b(c0.y); af[2]=f2b(c0.z); af[3]=f2b(c0.w);
        af[4]=f2b(c1.x); af[5]=f2b(c1.y); af[6]=f2b(c1.z); af[7]=f2b(c1.w);
        #pragma unroll
        for (int nf = 0; nf < 8; ++nf) {
            bf16x8 bf = *(const bf16x8*)(&cur[(nf*64 + lane) * 8]);
            acc[nf] = __builtin_amdgcn_mfma_f32_16x16x32_bf16(af, bf, acc[nf], 0, 0, 0);
        }
        c0 = n0; c1 = n1;
        __syncthreads();
    }

    // relu + bf16 -> wave-private slab; stage vwF chunk 0
    #pragma unroll
    for (int nf = 0; nf < 8; ++nf)
        #pragma unroll
        for (int i = 0; i < 4; ++i)
            Sb[(wrow + lhi*4 + i) * 136 + nf*16 + l15] = f2b(fmaxf(acc[nf][i], 0.f));
    {
        const int4* s = (const int4*)vwF;
        int4* d = (int4*)WbA;
        d[tid] = s[tid]; d[tid + 256] = s[tid + 256];
    }
    __syncthreads();

    f32x4 acc2[8];
    #pragma unroll
    for (int b = 0; b < 8; ++b) acc2[b] = (f32x4){0.f, 0.f, 0.f, 0.f};

    #pragma unroll
    for (int ks = 0; ks < 4; ++ks) {
        short* cur = (ks & 1) ? WbB : WbA;
        short* nxt = (ks & 1) ? WbA : WbB;
        if (ks < 3) {
            const int4* s = (const int4*)(vwF + (ks + 1) * 4096);
            int4* d = (int4*)nxt;
            d[tid] = s[tid]; d[tid + 256] = s[tid + 256];
        }
        bf16x8 af2 = *(const bf16x8*)(&Sb[(wrow + l15) * 136 + ks*32 + lhi*8]);
        #pragma unroll
        for (int nf = 0; nf < 8; ++nf) {
            bf16x8 bf2 = *(const bf16x8*)(&cur[(nf*64 + lane) * 8]);
            acc2[nf] = __builtin_amdgcn_mfma_f32_16x16x32_bf16(af2, bf2, acc2[nf], 0, 0, 0);
        }
        __syncthreads();
    }

    #pragma unroll
    for (int nf = 0; nf < 8; ++nf)
        #pragma unroll
        for (int i = 0; i < 4; ++i)
            Sb[(wrow + lhi*4 + i) * 136 + nf*16 + l15] = f2b(acc2[nf][i]);

    const int srow = lane >> 2;
    const int sch  = (lane & 3) * 32;
    const int gr_s = bm + wrow + srow;
    if (gr_s < M) {
        #pragma unroll
        for (int r = 0; r < 4; ++r) {
            float4 t = *(const float4*)(&Sb[(wrow + srow) * 136 + sch + r*8]);
            *(float4*)(Yb + (size_t)gr_s * EDIM + sch + r*8) = t;
        }
    }
}

// ---------------------------------------------------------------------------
// Gather2: block = one 128-row half-range. Build EXACT CSR in LDS from the
// binned list (count -> serial scan -> scatter; LDS atomics only), then each
// wave gathers 32 rows: out[row] = Aa*sum w*Y[col] + Bb*Y[row] + 2*vb.
// All global stores coalesced; no degree cap (exact computation).
// ---------------------------------------------------------------------------
__global__ __launch_bounds__(256) void k_gather2(const uint2* __restrict__ binned,
                                                 const int* __restrict__ gtail,
                                                 const __hip_bfloat162* __restrict__ Yb,
                                                 const float* __restrict__ vb,
                                                 const float* __restrict__ sc,
                                                 float* __restrict__ out, int M) {
    __shared__ unsigned csr[CSRCAP];   // packed {col<<16 | bf16(w)}
    __shared__ int cnt[128], off[128], cur[128];
    const int tid = threadIdx.x, wave = tid >> 6, lane = tid & 63;
    const int rg = blockIdx.x >> 1, half = blockIdx.x & 1;
    int n = gtail[rg]; if (n > RCAP) n = RCAP;
    const uint2* src = binned + (size_t)rg * RCAP;

    if (tid < 128) cnt[tid] = 0;
    __syncthreads();
    for (int i = tid; i < n; i += 256) {               // count
        int r8 = (src[i].x >> 16) & 255;
        if ((r8 >> 7) == half) atomicAdd(&cnt[r8 & 127], 1);
    }
    __syncthreads();
    if (tid == 0) {                                    // exclusive scan
        int s = 0;
        for (int i = 0; i < 128; ++i) { off[i] = s; s += cnt[i]; }
    }
    __syncthreads();
    if (tid < 128) cur[tid] = off[tid];
    __syncthreads();
    for (int i = tid; i < n; i += 256) {               // scatter
        uint2 ent = src[i];
        int r8 = (ent.x >> 16) & 255;
        if ((r8 >> 7) == half) {
            int pos = atomicAdd(&cur[r8 & 127], 1);
            if (pos < CSRCAP)
                csr[pos] = ((ent.x & 0xFFFFu) << 16) |
                           (unsigned short)f2b(__uint_as_float(ent.y));
        }
    }
    __syncthreads();

    const float Aa = sc[0], Bb = sc[1];
    for (int s = 0; s < 32; ++s) {
        int lr  = wave * 32 + s;
        int row = rg * 256 + half * 128 + lr;
        if (row >= M) break;
        int b0 = off[lr];
        int c  = cnt[lr];
        if (b0 + c > CSRCAP) c = max(0, CSRCAP - b0);
        float2 acc = make_float2(0.f, 0.f);
        int j = 0;
        for (; j + 8 <= c; j += 8) {
            float2 v[8]; float w[8];
            #pragma unroll
            for (int u = 0; u < 8; ++u) {
                unsigned e = csr[b0 + j + u];
                w[u] = __uint_as_float(e << 16);
                v[u] = __bfloat1622float2(Yb[(size_t)(e >> 16) * 64 + lane]);
            }
            #pragma unroll
            for (int u = 0; u < 8; ++u) {
                acc.x = fmaf(w[u], v[u].x, acc.x);
                acc.y = fmaf(w[u], v[u].y, acc.y);
            }
        }
        for (; j < c; ++j) {
            unsigned e = csr[b0 + j];
            float w = __uint_as_float(e << 16);
            float2 v = __bfloat1622float2(Yb[(size_t)(e >> 16) * 64 + lane]);
            acc.x = fmaf(w, v.x, acc.x);
            acc.y = fmaf(w, v.y, acc.y);
        }
        float2 y = __bfloat1622float2(Yb[(size_t)row * 64 + lane]);
        float2 b = *(const float2*)(vb + lane * 2);
        float2 o;
        o.x = fmaf(Aa, acc.x, fmaf(Bb, y.x, 2.f * b.x));
        o.y = fmaf(Aa, acc.y, fmaf(Bb, y.y, 2.f * b.y));
        *(float2*)(out + (size_t)row * EDIM + lane * 2) = o;
    }
}

// ---------------------------------------------------------------------------
extern "C" void kernel_launch(void* const* d_in, const int* in_sizes, int n_in,
                              void* d_out, int out_size, void* d_ws, size_t ws_size,
                              hipStream_t stream) {
    const float* feature = (const float*)d_in[0];
    const int*   eidx    = (const int*)d_in[1];   // [2, NE] int32
    const float* ew      = (const float*)d_in[2];
    const float* weight  = (const float*)d_in[3];
    const float* lg      = (const float*)d_in[4];
    const float* mg      = (const float*)d_in[5];
    // d_in[6..9] = q_w,q_b,k_w,k_b provably unused: softmax over the query axis
    // followed by sum over the query axis makes each k-column of w sum to 1.
    const float* vw      = (const float*)d_in[10];
    const float* vb      = (const float*)d_in[11];
    float* out = (float*)d_out;

    const int M  = in_sizes[0] / FIN;   // 50000 (col fits u16; ranges <= 256)
    const int NE = in_sizes[2];         // 600000

    // workspace layout (~20 MB)
    char* ws = (char*)d_ws;
    short* Yb      = (short*)ws;                                  // 12.8 MB
    char* p = ws + (size_t)M * EDIM * 2;
    uint2* binned  = (uint2*)p;      p += (size_t)256 * RCAP * 8; // 7.1 MB
    int*   gtail   = (int*)p;        p += 256 * 4;
    short* WtF     = (short*)p;      p += (size_t)EDIM * FIN * 2;   // 64 KB
    short* vwF     = (short*)p;      p += (size_t)EDIM * EDIM * 2;  // 32 KB
    float* sc      = (float*)p;

    k_prep<<<26, 256, 0, stream>>>(weight, vw, lg, mg, WtF, vwF, sc, gtail);

    const int gGemm = (M + 63) / 64;
    k_mega<<<NBIN + gGemm, 256, 0, stream>>>(feature, WtF, vwF, Yb,
                                             eidx, ew, gtail, binned, M, NE);

    const int ranges = (M + 255) / 256;
    k_gather2<<<ranges * 2, 256, 0, stream>>>(binned, gtail,
                                              (const __hip_bfloat162*)Yb,
                                              vb, sc, out, M);
}

// Round 15
// 105.656 us; speedup vs baseline: 6.9127x; 6.9127x over previous
//
#include <hip/hip_runtime.h>
#include <hip/hip_bf16.h>

static constexpr int EDIM = 128;   // embedding size
static constexpr int FIN  = 256;   // input features
static constexpr int CAP  = 64;    // per-row edge bucket capacity (deg~Poisson(12))

typedef __attribute__((ext_vector_type(8))) short bf16x8;
typedef __attribute__((ext_vector_type(4))) float f32x4;

__device__ inline short f2b(float f) {
    __hip_bfloat16 h = __float2bfloat16(f);
    return *reinterpret_cast<short*>(&h);
}

// ---------------------------------------------------------------------------
// Prep: fragment-major bf16 weights + scalar coefficients + zero cnt[].
//   WtF[((kt*8+nf)*64+lane)] = B-frag of W    (4096 frags, 64 KB; chunk kt = 8KB)
//   vwF[((ks*8+nf)*64+lane)] = B-frag of vw^T (2048 frags, 32 KB; chunk ks = 8KB)
// ---------------------------------------------------------------------------
__global__ __launch_bounds__(256) void k_prep(const float* __restrict__ W,
                                              const float* __restrict__ vw,
                                              const float* __restrict__ lg,
                                              const float* __restrict__ mg,
                                              short* __restrict__ WtF,
                                              short* __restrict__ vwF,
                                              float* __restrict__ sc,
                                              int* __restrict__ cnt, int M) {
    const int bid = blockIdx.x, tid = threadIdx.x;
    if (bid < 16) {                                // WtF: 4096 fragments
        int idx = bid * 256 + tid;                 // (kt,nf,lane)
        int kt = idx >> 9, rem = idx & 511;
        int nf = rem >> 6, lane = rem & 63;
        int l15 = lane & 15, lhi = lane >> 4;
        bf16x8 fr;
        #pragma unroll
        for (int i = 0; i < 8; ++i)
            fr[i] = f2b(W[(size_t)(kt*32 + lhi*8 + i) * EDIM + nf*16 + l15]);
        *(bf16x8*)(WtF + (size_t)idx * 8) = fr;
    } else if (bid < 24) {                         // vwF: 2048 fragments
        int idx = (bid - 16) * 256 + tid;          // (ks,nf,lane)
        int ks = idx >> 9, rem = idx & 511;
        int nf = rem >> 6, lane = rem & 63;
        int l15 = lane & 15, lhi = lane >> 4;
        bf16x8 fr;
        #pragma unroll
        for (int i = 0; i < 8; ++i)
            fr[i] = f2b(vw[(size_t)(nf*16 + l15) * EDIM + ks*32 + lhi*8 + i]);
        *(bf16x8*)(vwF + (size_t)idx * 8) = fr;
    } else if (bid == 24) {
        if (tid == 0) {
            const float a0 = -1e-9f, a1 = 1.0f + 1e-9f;
            float a_low = 0.f, b_low = 0.f, a_mid = 0.f, c_mid = 0.f;
            for (int i = 0; i < 5; ++i) {
                float l0 = fmaxf(lg[2*i], 0.f), l1 = fmaxf(lg[2*i+1], 0.f);
                a_low += l0 * a0 + l1 * a1;
                b_low += l0 * (1.f - a0) + l1 * (1.f - a1);
                float m0 = fmaxf(mg[2*i], 0.f), m1 = fmaxf(mg[2*i+1], 0.f);
                a_mid += m0 + m1;
                c_mid += m0 * a0 + m1 * a1;
            }
            sc[0] = a_low + a_mid;
            sc[1] = b_low - c_mid;
        }
    } else {
        int i = (bid - 25) * 256 + tid;
        if (i < M) cnt[i] = 0;
    }
}

// ---------------------------------------------------------------------------
// Mega dispatch (33.8 KB LDS -> 4 blocks/CU):
//  blocks [0, gGemm): fused MFMA GEMM Y = relu(F@W) @ vw^T. BM=64, 4 waves,
//    wave owns 16 rows. 8KB weight chunks double-buffered in LDS; F loaded
//    2x float4 per k-step with 1-step prefetch (no spill).
//  blocks [gGemm, +NFILL): XCD-partitioned grid-strided bucket fill, packed
//    4B entries bkt[r*CAP+pos] = (col<<16)|bf16(w), via NON-TEMPORAL stores
//    (bypass L2 line allocation: kills the 64B-per-scattered-store writeback
//    tax measured at 38MB in r6-r13, and stops evicting gemm/Yb lines).
//    Edge reads are non-temporal too (read-once stream). cnt[] atomics stay
//    XCD-local via the partition<->bid%8 mapping.
// ---------------------------------------------------------------------------
__global__ __launch_bounds__(256) void k_mega(const float* __restrict__ F,
                                              const short* __restrict__ WtF,
                                              const short* __restrict__ vwF,
                                              short* __restrict__ Yb,
                                              const int* __restrict__ ei,
                                              const float* __restrict__ ew,
                                              int* __restrict__ cnt,
                                              unsigned* __restrict__ bkt,
                                              int M, int ne, int R, int nFill) {
    __shared__ short Sb[64 * 136];   // 17408 B wave-private transpose slabs
    __shared__ short Wb[2][4096];    // 2 x 8KB weight-chunk double buffer
    const int gGemm = (M + 63) >> 6;
    const int bid = blockIdx.x, tid = threadIdx.x;

    if (bid >= gGemm) {              // ---- bucket-fill path ----
        int bid2 = bid - gGemm;
        int part = bid2 & 7;
        int lo = part * R, hi = lo + R;
        int stride = (nFill >> 3) * 256;
        for (int e = (bid2 >> 3) * 256 + tid; e < ne; e += stride) {
            int r = __builtin_nontemporal_load(ei + e);
            if (r >= lo && r < hi) {
                int pos = atomicAdd(&cnt[r], 1);
                if (pos < CAP) {
                    unsigned col = (unsigned)__builtin_nontemporal_load(ei + ne + e);
                    float    w   = __builtin_nontemporal_load(ew + e);
                    unsigned pk  = (col << 16) | (unsigned short)f2b(w);
                    __builtin_nontemporal_store(pk, bkt + (size_t)r * CAP + pos);
                }
            }
        }
        return;
    }

    // ---- fused GEMM path ----
    const int wave = tid >> 6, lane = tid & 63;
    const int l15  = lane & 15, lhi = lane >> 4;
    const int bm   = bid * 64;
    const int wrow = wave * 16;

    const int gr_a = bm + wrow + l15;
    const bool va  = gr_a < M;
    const float* fp = F + (size_t)(va ? gr_a : 0) * FIN + lhi * 8;

    // stage chunk 0 of WtF
    {
        const int4* s = (const int4*)WtF;
        int4* d = (int4*)Wb[0];
        d[tid] = s[tid]; d[tid + 256] = s[tid + 256];
    }
    float4 c0 = make_float4(0.f,0.f,0.f,0.f), c1 = c0;
    if (va) { c0 = *(const float4*)(fp); c1 = *(const float4*)(fp + 4); }
    __syncthreads();

    f32x4 acc[8];
    #pragma unroll
    for (int b = 0; b < 8; ++b) acc[b] = (f32x4){0.f, 0.f, 0.f, 0.f};

    // GEMM1: sup = relu(F @ W), 8 chunks, double-buffered
    #pragma unroll
    for (int kt = 0; kt < 8; ++kt) {
        const int cur = kt & 1;
        if (kt < 7) {                          // stage next chunk into other buf
            const int4* s = (const int4*)(WtF + (kt + 1) * 4096);
            int4* d = (int4*)Wb[cur ^ 1];
            d[tid] = s[tid]; d[tid + 256] = s[tid + 256];
        }
        float4 n0 = make_float4(0.f,0.f,0.f,0.f), n1 = n0;
        if (kt < 7 && va) {
            n0 = *(const float4*)(fp + (kt+1)*32);
            n1 = *(const float4*)(fp + (kt+1)*32 + 4);
        }
        bf16x8 af;
        af[0]=f2b(c0.x); af[1]=f2b(c0.y); af[2]=f2b(c0.z); af[3]=f2b(c0.w);
        af[4]=f2b(c1.x); af[5]=f2b(c1.y); af[6]=f2b(c1.z); af[7]=f2b(c1.w);
        #pragma unroll
        for (int nf = 0; nf < 8; ++nf) {
            bf16x8 bf = *(const bf16x8*)(&Wb[cur][(nf*64 + lane) * 8]);
            acc[nf] = __builtin_amdgcn_mfma_f32_16x16x32_bf16(af, bf, acc[nf], 0, 0, 0);
        }
        c0 = n0; c1 = n1;
        __syncthreads();                       // all waves done with Wb[cur]
    }

    // relu + bf16 -> wave-private slab; stage vwF chunk 0
    #pragma unroll
    for (int nf = 0; nf < 8; ++nf)
        #pragma unroll
        for (int i = 0; i < 4; ++i)
            Sb[(wrow + lhi*4 + i) * 136 + nf*16 + l15] = f2b(fmaxf(acc[nf][i], 0.f));
    {
        const int4* s = (const int4*)vwF;
        int4* d = (int4*)Wb[0];
        d[tid] = s[tid]; d[tid + 256] = s[tid + 256];
    }
    __syncthreads();

    // GEMM2: Y = sup @ vw^T, 4 chunks, double-buffered
    f32x4 acc2[8];
    #pragma unroll
    for (int b = 0; b < 8; ++b) acc2[b] = (f32x4){0.f, 0.f, 0.f, 0.f};

    #pragma unroll
    for (int ks = 0; ks < 4; ++ks) {
        const int cur = ks & 1;
        if (ks < 3) {
            const int4* s = (const int4*)(vwF + (ks + 1) * 4096);
            int4* d = (int4*)Wb[cur ^ 1];
            d[tid] = s[tid]; d[tid + 256] = s[tid + 256];
        }
        bf16x8 af2 = *(const bf16x8*)(&Sb[(wrow + l15) * 136 + ks*32 + lhi*8]);
        #pragma unroll
        for (int nf = 0; nf < 8; ++nf) {
            bf16x8 bf2 = *(const bf16x8*)(&Wb[cur][(nf*64 + lane) * 8]);
            acc2[nf] = __builtin_amdgcn_mfma_f32_16x16x32_bf16(af2, bf2, acc2[nf], 0, 0, 0);
        }
        __syncthreads();
    }

    // Y -> slab (own wave's rows; same-wave RAW handled by lgkmcnt)
    #pragma unroll
    for (int nf = 0; nf < 8; ++nf)
        #pragma unroll
        for (int i = 0; i < 4; ++i)
            Sb[(wrow + lhi*4 + i) * 136 + nf*16 + l15] = f2b(acc2[nf][i]);

    const int srow = lane >> 2;                    // 16 rows, 4 lanes each
    const int sch  = (lane & 3) * 32;              // 64B chunk of the row
    const int gr_s = bm + wrow + srow;
    if (gr_s < M) {
        #pragma unroll
        for (int r = 0; r < 4; ++r) {
            float4 t = *(const float4*)(&Sb[(wrow + srow) * 136 + sch + r*8]);
            *(float4*)(Yb + (size_t)gr_s * EDIM + sch + r*8) = t;
        }
    }
}

// ---------------------------------------------------------------------------
// Fused gather + epilogue: out[row] = Aa * sum_e w_e * Y[col_e] + Bb*Y[row] + 2*vb
// One wave per row; packed 4B bucket entries; 8-way unrolled.
// ---------------------------------------------------------------------------
__global__ __launch_bounds__(256) void k_gather(const unsigned* __restrict__ bkt,
                                                const int* __restrict__ cnt,
                                                const __hip_bfloat162* __restrict__ Yb,
                                                const float* __restrict__ vb,
                                                const float* __restrict__ sc,
                                                float* __restrict__ out, int n) {
    int row  = (blockIdx.x * blockDim.x + threadIdx.x) >> 6;
    int lane = threadIdx.x & 63;
    if (row >= n) return;
    int c = __builtin_amdgcn_readfirstlane(cnt[row]);
    if (c > CAP) c = CAP;
    const unsigned* bucket = bkt + (size_t)row * CAP;
    const float Aa = sc[0];
    const float Bb = sc[1];

    float2 acc = make_float2(0.f, 0.f);
    int j = 0;
    for (; j + 8 <= c; j += 8) {
        float2 v[8]; float w[8];
        #pragma unroll
        for (int u = 0; u < 8; ++u) {
            unsigned e = bucket[j + u];
            w[u] = __uint_as_float(e << 16);           // bf16 -> f32
            v[u] = __bfloat1622float2(Yb[(size_t)(e >> 16) * 64 + lane]);
        }
        #pragma unroll
        for (int u = 0; u < 8; ++u) {
            acc.x = fmaf(w[u], v[u].x, acc.x);
            acc.y = fmaf(w[u], v[u].y, acc.y);
        }
    }
    for (; j + 4 <= c; j += 4) {
        float2 v[4]; float w[4];
        #pragma unroll
        for (int u = 0; u < 4; ++u) {
            unsigned e = bucket[j + u];
            w[u] = __uint_as_float(e << 16);
            v[u] = __bfloat1622float2(Yb[(size_t)(e >> 16) * 64 + lane]);
        }
        #pragma unroll
        for (int u = 0; u < 4; ++u) {
            acc.x = fmaf(w[u], v[u].x, acc.x);
            acc.y = fmaf(w[u], v[u].y, acc.y);
        }
    }
    for (; j < c; ++j) {
        unsigned e = bucket[j];
        float w = __uint_as_float(e << 16);
        float2 v = __bfloat1622float2(Yb[(size_t)(e >> 16) * 64 + lane]);
        acc.x = fmaf(w, v.x, acc.x);
        acc.y = fmaf(w, v.y, acc.y);
    }
    float2 y = __bfloat1622float2(Yb[(size_t)row * 64 + lane]);
    float2 b = *(const float2*)(vb + lane * 2);
    float2 o;
    o.x = fmaf(Aa, acc.x, fmaf(Bb, y.x, 2.f * b.x));
    o.y = fmaf(Aa, acc.y, fmaf(Bb, y.y, 2.f * b.y));
    *(float2*)(out + (size_t)row * EDIM + lane * 2) = o;
}

// ---------------------------------------------------------------------------
extern "C" void kernel_launch(void* const* d_in, const int* in_sizes, int n_in,
                              void* d_out, int out_size, void* d_ws, size_t ws_size,
                              hipStream_t stream) {
    const float* feature = (const float*)d_in[0];
    const int*   eidx    = (const int*)d_in[1];   // [2, NE] int32
    const float* ew      = (const float*)d_in[2];
    const float* weight  = (const float*)d_in[3];
    const float* lg      = (const float*)d_in[4];
    const float* mg      = (const float*)d_in[5];
    // d_in[6..9] = q_w,q_b,k_w,k_b provably unused: softmax over the query axis
    // followed by sum over the query axis makes each k-column of w sum to 1.
    const float* vw      = (const float*)d_in[10];
    const float* vb      = (const float*)d_in[11];
    float* out = (float*)d_out;

    const int M  = in_sizes[0] / FIN;   // 50000
    const int NE = in_sizes[2];         // 600000

    // workspace layout (~26 MB)
    char* ws = (char*)d_ws;
    short* Yb      = (short*)ws;                                // 12.8 MB
    char* p = ws + (size_t)M * EDIM * 2;
    unsigned* bkt  = (unsigned*)p;   p += (size_t)M * CAP * 4;  // 12.8 MB packed
    int*   cnt     = (int*)p;        p += (size_t)M * 4;        // 200 KB
    short* WtF     = (short*)p;      p += (size_t)EDIM * FIN * 2;  // 64 KB
    short* vwF     = (short*)p;      p += (size_t)EDIM * EDIM * 2; // 32 KB
    float* sc      = (float*)p;

    const int nb = (M + 255) / 256;
    const int R  = (M + 7) / 8;               // rows per XCD partition
    const int NFILL = 2048;                   // grid-strided fill blocks

    k_prep<<<25 + nb, 256, 0, stream>>>(weight, vw, lg, mg, WtF, vwF, sc, cnt, M);

    const int gGemm = (M + 63) / 64;
    k_mega<<<gGemm + NFILL, 256, 0, stream>>>(feature, WtF, vwF, Yb,
                                              eidx, ew, cnt, bkt, M, NE, R, NFILL);

    int gGather = ((M * 64) + 255) / 256;     // one wave per row
    k_gather<<<gGather, 256, 0, stream>>>(bkt, cnt, (const __hip_bfloat162*)Yb,
                                          vb, sc, out, M);
}